// Round 7
// baseline (105.732 us; speedup 1.0000x reference)
//
#include <hip/hip_runtime.h>
#include <hip/hip_bf16.h>

#define DN 128
#define DE 64
#define NN 512

typedef __bf16 bf16x8 __attribute__((ext_vector_type(8)));
typedef float  f32x4  __attribute__((ext_vector_type(4)));

// -------- fused prep (unchanged) --------------------------------------------
__global__ void prep_kernel(const float* __restrict__ nodes,
                            const float* __restrict__ g_node,
                            const float* __restrict__ g_edge,
                            const float* __restrict__ W,
                            const float* __restrict__ bias,
                            float* __restrict__ rp, float* __restrict__ cp,
                            __bf16* __restrict__ weg) {
    const int l = threadIdx.x;  // 0..63
    if (blockIdx.x == 1024) {
        const int kg = l >> 4;
        for (int kh = 0; kh < 2; ++kh)
            for (int ct = 0; ct < 4; ++ct) {
                const int f = kh * 4 + ct;
                #pragma unroll
                for (int e = 0; e < 8; ++e) {
                    const int k   = kh * 32 + (e >> 2) * 16 + kg * 4 + (e & 3);
                    const int col = ct * 16 + (l & 15);
                    weg[(f * 64 + l) * 8 + e] =
                        (__bf16)(g_edge[k] * W[(2 * DN + k) * DE + col]);
                }
            }
        return;
    }
    const int row = blockIdx.x;      // b*N + i
    __shared__ float nn[DN];

    float x0 = nodes[row * DN + l];
    float x1 = nodes[row * DN + l + 64];
    float ssq = x0 * x0 + x1 * x1;
    #pragma unroll
    for (int m = 1; m < 64; m <<= 1) ssq += __shfl_xor(ssq, m, 64);
    float scale = rsqrtf(ssq * (1.0f / DN) + 1.1920929e-7f);
    nn[l]      = x0 * scale * g_node[l];
    nn[l + 64] = x1 * scale * g_node[l + 64];
    __syncthreads();

    float accr = bias[l];
    float accc = 0.0f;
    #pragma unroll 4
    for (int d = 0; d < DN; ++d) {
        float nd = nn[d];
        accr += nd * W[d * DE + l];          // Wr = W[0:128]
        accc += nd * W[(DN + d) * DE + l];   // Wc = W[128:256]
    }
    rp[row * DE + l] = accr;
    cp[row * DE + l] = accc;
}

// -------- main: wave-independent 4-tile pipeline, counted vmcnt -------------
// grid 2048 x 256. row = bid>>1, j-half = (bid&1)*256; wave w owns j in
// [jh + w*64, +64) = 4 tiles of 16 rows. LDS: wave w gets 8 KB = 2 x 4 KB
// double buffer. Per tile: stage(t+1) via global_load_lds (linear dest,
// inverse-XOR-swz source, full 128B lines) + cp(t+1) prefetch, then
// s_waitcnt vmcnt(12) (prev stores + next-tile loads stay IN FLIGHT),
// compute tile t (swizzled ds_read frags, 2 shfl_xor ssq, 8 MFMA, epilogue
// ds_write), linear LDS read -> full-line stores. No __syncthreads anywhere;
// emission order pinned with sched_barrier so vmcnt immediates are exact.
__global__ __launch_bounds__(256, 4) void main_kernel(
    const float* __restrict__ edges, const float* __restrict__ rp,
    const float* __restrict__ cp, const __bf16* __restrict__ weg,
    float* __restrict__ out) {
    __shared__ float lds[8192];            // 32 KB; wave w: [w*2048, +2048)
    const int bid = blockIdx.x;            // 0..2047
    const int row = bid >> 1;              // b*N + i
    const int t4  = threadIdx.x;           // 0..255
    const int w   = t4 >> 6;
    const int l   = t4 & 63;
    const int r16 = l & 15;
    const int kg  = l >> 4;
    const int jb  = (bid & 1) * 256 + w * 64;  // wave j-base; tiles jb + t*16
    const int bN  = (row >> 9) << 9;       // b*512

    float* wlds = &lds[w * 2048];
    const float* tbase = edges + ((size_t)row * NN + jb) * DE;   // wave's 16 KB
    float*       obase = out   + ((size_t)row * NN + jb) * DE;

    // ---- prologue: reg operands + stage tile0 + cp tile0 (20 VMEM ops) ----
    bf16x8 wf[8];
    #pragma unroll
    for (int f = 0; f < 8; ++f)
        wf[f] = *reinterpret_cast<const bf16x8*>(weg + (f * 64 + l) * 8);

    f32x4 rpv[4];
    #pragma unroll
    for (int c = 0; c < 4; ++c)
        rpv[c] = *reinterpret_cast<const f32x4*>(rp + row * DE + c * 16 + kg * 4);

    const float* cpbase = cp + (size_t)(bN + jb + r16) * DE + kg * 4;

    #pragma unroll
    for (int i = 0; i < 4; ++i) {          // stage(buf0, t=0)
        const int C = i * 64 + l;
        const int r = C >> 4;
        const int q = (C & 15) ^ r;
        __builtin_amdgcn_global_load_lds(
            (const __attribute__((address_space(1))) void*)(tbase + r * DE + q * 4),
            (__attribute__((address_space(3))) void*)(&wlds[i * 256]),
            16, 0, 0);
    }
    f32x4 cpv[2][4];
    #pragma unroll
    for (int c = 0; c < 4; ++c)
        cpv[0][c] = *reinterpret_cast<const f32x4*>(cpbase + c * 16);

    __builtin_amdgcn_sched_barrier(0);

    #pragma unroll
    for (int t = 0; t < 4; ++t) {
        const int p = t & 1;
        // ---- issue next tile's loads FIRST (stay in flight across compute) --
        if (t < 3) {
            #pragma unroll
            for (int i = 0; i < 4; ++i) {
                const int C = i * 64 + l;
                const int r = C >> 4;
                const int q = (C & 15) ^ r;
                __builtin_amdgcn_global_load_lds(
                    (const __attribute__((address_space(1))) void*)
                        (tbase + ((t + 1) * 16 + r) * DE + q * 4),
                    (__attribute__((address_space(3))) void*)
                        (&wlds[(p ^ 1) * 1024 + i * 256]),
                    16, 0, 0);
            }
            #pragma unroll
            for (int c = 0; c < 4; ++c)
                cpv[p ^ 1][c] = *reinterpret_cast<const f32x4*>(
                    cpbase + (t + 1) * 16 * DE + c * 16);
        }
        __builtin_amdgcn_sched_barrier(0);
        // ensure stage(t)+cp(t) complete; keep prev stores + next loads in flight
        if (t == 0)      asm volatile("s_waitcnt vmcnt(8)"  ::: "memory");
        else if (t < 3)  asm volatile("s_waitcnt vmcnt(12)" ::: "memory");
        else             asm volatile("s_waitcnt vmcnt(4)"  ::: "memory");
        __builtin_amdgcn_sched_barrier(0);

        // ---- fragments from LDS buf p (swizzled reads, bank-balanced) ----
        f32x4 x[4];
        #pragma unroll
        for (int m = 0; m < 4; ++m) {
            const int q = (m * 4 + kg) ^ r16;
            x[m] = *reinterpret_cast<const f32x4*>(&wlds[p * 1024 + r16 * 64 + q * 4]);
        }

        float ssq = 0.0f;
        #pragma unroll
        for (int m = 0; m < 4; ++m)
            #pragma unroll
            for (int e = 0; e < 4; ++e) ssq += x[m][e] * x[m][e];
        ssq += __shfl_xor(ssq, 16, 64);
        ssq += __shfl_xor(ssq, 32, 64);
        const float scale = rsqrtf(ssq * (1.0f / DE) + 1.1920929e-7f);

        bf16x8 a0, a1;
        #pragma unroll
        for (int e = 0; e < 4; ++e) {
            a0[e]     = (__bf16)x[0][e];   // k = kg*4+e
            a0[e + 4] = (__bf16)x[1][e];   // k = 16+kg*4+e
            a1[e]     = (__bf16)x[2][e];   // k = 32+kg*4+e
            a1[e + 4] = (__bf16)x[3][e];   // k = 48+kg*4+e
        }

        #pragma unroll
        for (int c = 0; c < 4; ++c) {
            f32x4 z = {0.f, 0.f, 0.f, 0.f};
            z = __builtin_amdgcn_mfma_f32_16x16x32_bf16(wf[c],     a0, z, 0, 0, 0);
            z = __builtin_amdgcn_mfma_f32_16x16x32_bf16(wf[4 + c], a1, z, 0, 0, 0);
            f32x4 o;
            #pragma unroll
            for (int r = 0; r < 4; ++r)
                o[r] = z[r] * scale + rpv[c][r] + cpv[p][c][r];
            const int qo = (c * 4 + kg) ^ r16;   // swizzled LDS write-back
            *reinterpret_cast<f32x4*>(&wlds[p * 1024 + r16 * 64 + qo * 4]) = o;
        }

        asm volatile("s_waitcnt lgkmcnt(0)" ::: "memory");
        __builtin_amdgcn_sched_barrier(0);

        // ---- LDS linear -> global, full-line stores (fire-and-forget) ----
        #pragma unroll
        for (int i = 0; i < 4; ++i) {
            const int C = i * 64 + l;
            const int r = C >> 4;
            const int q = (C & 15) ^ r;
            f32x4 v = *reinterpret_cast<const f32x4*>(&wlds[p * 1024 + C * 4]);
            *reinterpret_cast<f32x4*>(obase + (t * 16 + r) * DE + q * 4) = v;
        }
        __builtin_amdgcn_sched_barrier(0);
    }
}

extern "C" void kernel_launch(void* const* d_in, const int* in_sizes, int n_in,
                              void* d_out, int out_size, void* d_ws, size_t ws_size,
                              hipStream_t stream) {
    const float* edges  = (const float*)d_in[0];
    const float* nodes  = (const float*)d_in[1];
    const float* g_node = (const float*)d_in[2];
    const float* g_edge = (const float*)d_in[3];
    const float* W      = (const float*)d_in[4];
    const float* bias   = (const float*)d_in[5];
    float* out = (float*)d_out;

    float*  rp  = (float*)d_ws;                 // 1024*64 f32 = 256 KB
    float*  cp  = rp + 1024 * DE;               // 256 KB
    __bf16* weg = (__bf16*)(cp + 1024 * DE);    // 8*64*8 bf16 = 8 KB

    prep_kernel<<<dim3(1025), dim3(64), 0, stream>>>(nodes, g_node, g_edge, W,
                                                     bias, rp, cp, weg);
    main_kernel<<<dim3(2048), dim3(256), 0, stream>>>(edges, rp, cp, weg, out);
}

// Round 8
// 60.816 us; speedup vs baseline: 1.7386x; 1.7386x over previous
//
#include <hip/hip_runtime.h>
#include <hip/hip_bf16.h>

#define DN 128
#define DE 64
#define NN 512

typedef __bf16 bf16x8 __attribute__((ext_vector_type(8)));
typedef float  f32x4  __attribute__((ext_vector_type(4)));

// -------- fused prep (unchanged) --------------------------------------------
__global__ void prep_kernel(const float* __restrict__ nodes,
                            const float* __restrict__ g_node,
                            const float* __restrict__ g_edge,
                            const float* __restrict__ W,
                            const float* __restrict__ bias,
                            float* __restrict__ rp, float* __restrict__ cp,
                            __bf16* __restrict__ weg) {
    const int l = threadIdx.x;  // 0..63
    if (blockIdx.x == 1024) {
        const int kg = l >> 4;
        for (int kh = 0; kh < 2; ++kh)
            for (int ct = 0; ct < 4; ++ct) {
                const int f = kh * 4 + ct;
                #pragma unroll
                for (int e = 0; e < 8; ++e) {
                    const int k   = kh * 32 + (e >> 2) * 16 + kg * 4 + (e & 3);
                    const int col = ct * 16 + (l & 15);
                    weg[(f * 64 + l) * 8 + e] =
                        (__bf16)(g_edge[k] * W[(2 * DN + k) * DE + col]);
                }
            }
        return;
    }
    const int row = blockIdx.x;      // b*N + i
    __shared__ float nn[DN];

    float x0 = nodes[row * DN + l];
    float x1 = nodes[row * DN + l + 64];
    float ssq = x0 * x0 + x1 * x1;
    #pragma unroll
    for (int m = 1; m < 64; m <<= 1) ssq += __shfl_xor(ssq, m, 64);
    float scale = rsqrtf(ssq * (1.0f / DN) + 1.1920929e-7f);
    nn[l]      = x0 * scale * g_node[l];
    nn[l + 64] = x1 * scale * g_node[l + 64];
    __syncthreads();

    float accr = bias[l];
    float accc = 0.0f;
    #pragma unroll 4
    for (int d = 0; d < DN; ++d) {
        float nd = nn[d];
        accr += nd * W[d * DE + l];          // Wr = W[0:128]
        accc += nd * W[(DN + d) * DE + l];   // Wc = W[128:256]
    }
    rp[row * DE + l] = accr;
    cp[row * DE + l] = accc;
}

// -------- main: wave-independent bounce, MONOTONIC global addressing --------
// grid 8192 x 256, zero __syncthreads (R6 structure). The one change vs R6:
// global loads/stores are plain dwordx4 with PURE ascending lane->address
// (lane l <-> byte l*16, copy-bench-identical); the XOR swizzle moved to the
// LDS side (ds_write_b128 swizzled dest / ds_read_b128 swizzled src), where
// the permute is free (bank-uniform: each 16-lane row-group covers all 16
// chunk slots of its 256 B row).
// Wave w owns tile rows [w*16, +16) and LDS [w*1024 floats, +1024).
__global__ __launch_bounds__(256, 4) void main_kernel(
    const float* __restrict__ edges, const float* __restrict__ rp,
    const float* __restrict__ cp, const __bf16* __restrict__ weg,
    float* __restrict__ out) {
    __shared__ float lds[4096];            // 16 KB; wave w: [w*1024, +1024)
    const int bid = blockIdx.x;            // 0..8191
    const int row = bid >> 3;              // b*N + i
    const int t   = threadIdx.x;           // 0..255
    const int w   = t >> 6;
    const int l   = t & 63;
    const int r16 = l & 15;
    const int kg  = l >> 4;
    const int jt0 = (bid & 7) * 64;        // tile j base (64 rows)
    const int bN  = (row >> 9) << 9;       // b*512

    float* wlds = &lds[w * 1024];
    const float* tbase = edges + ((size_t)row * NN + jt0 + w * 16) * DE;
    float*       obase = out   + ((size_t)row * NN + jt0 + w * 16) * DE;

    // ---- P1: plain ascending loads (copy-identical), 4 KB per wave ----
    f32x4 st[4];
    #pragma unroll
    for (int i = 0; i < 4; ++i)
        st[i] = *reinterpret_cast<const f32x4*>(tbase + (i * 64 + l) * 4);

    // ---- reg operands (L1/L2-hot) ----
    bf16x8 wf[8];
    #pragma unroll
    for (int f = 0; f < 8; ++f)
        wf[f] = *reinterpret_cast<const bf16x8*>(weg + (f * 64 + l) * 8);

    const int j = jt0 + w * 16 + r16;       // this lane's global j
    const float* cprow = cp + (size_t)(bN + j) * DE + kg * 4;
    f32x4 cpv[4];
    #pragma unroll
    for (int c = 0; c < 4; ++c)
        cpv[c] = *reinterpret_cast<const f32x4*>(cprow + c * 16);

    f32x4 rpv[4];
    #pragma unroll
    for (int c = 0; c < 4; ++c)
        rpv[c] = *reinterpret_cast<const f32x4*>(rp + row * DE + c * 16 + kg * 4);

    // ---- P2: staged regs -> LDS, swizzled dest (chunk c of row r -> c^r) ----
    #pragma unroll
    for (int i = 0; i < 4; ++i) {
        const int C = i * 64 + l;           // wave-local chunk (linear global)
        const int r = C >> 4;               // row within wave's 16
        const int q = (C & 15) ^ r;         // swizzled LDS chunk slot
        *reinterpret_cast<f32x4*>(&wlds[r * 64 + q * 4]) = st[i];
    }

    // ---- P3: fragments from LDS (swizzled reads; wave-local ordering) ----
    f32x4 x[4];
    #pragma unroll
    for (int m = 0; m < 4; ++m) {
        const int q = (m * 4 + kg) ^ r16;
        x[m] = *reinterpret_cast<const f32x4*>(&wlds[r16 * 64 + q * 4]);
    }

    float ssq = 0.0f;
    #pragma unroll
    for (int m = 0; m < 4; ++m)
        #pragma unroll
        for (int e = 0; e < 4; ++e) ssq += x[m][e] * x[m][e];
    ssq += __shfl_xor(ssq, 16, 64);
    ssq += __shfl_xor(ssq, 32, 64);
    const float scale = rsqrtf(ssq * (1.0f / DE) + 1.1920929e-7f);

    bf16x8 a0, a1;
    #pragma unroll
    for (int e = 0; e < 4; ++e) {
        a0[e]     = (__bf16)x[0][e];   // k = kg*4+e
        a0[e + 4] = (__bf16)x[1][e];   // k = 16+kg*4+e
        a1[e]     = (__bf16)x[2][e];   // k = 32+kg*4+e
        a1[e + 4] = (__bf16)x[3][e];   // k = 48+kg*4+e
    }

    #pragma unroll
    for (int c = 0; c < 4; ++c) {
        f32x4 z = {0.f, 0.f, 0.f, 0.f};
        z = __builtin_amdgcn_mfma_f32_16x16x32_bf16(wf[c],     a0, z, 0, 0, 0);
        z = __builtin_amdgcn_mfma_f32_16x16x32_bf16(wf[4 + c], a1, z, 0, 0, 0);
        f32x4 o;
        #pragma unroll
        for (int r = 0; r < 4; ++r)
            o[r] = z[r] * scale + rpv[c][r] + cpv[c][r];
        const int qo = (c * 4 + kg) ^ r16;  // swizzled LDS write-back
        *reinterpret_cast<f32x4*>(&wlds[r16 * 64 + qo * 4]) = o;
    }

    // ---- P5: swizzled LDS read -> plain ascending stores (copy-identical) --
    #pragma unroll
    for (int i = 0; i < 4; ++i) {
        const int C = i * 64 + l;
        const int r = C >> 4;
        const int q = (C & 15) ^ r;
        f32x4 v = *reinterpret_cast<const f32x4*>(&wlds[r * 64 + q * 4]);
        *reinterpret_cast<f32x4*>(obase + (i * 64 + l) * 4) = v;
    }
}

extern "C" void kernel_launch(void* const* d_in, const int* in_sizes, int n_in,
                              void* d_out, int out_size, void* d_ws, size_t ws_size,
                              hipStream_t stream) {
    const float* edges  = (const float*)d_in[0];
    const float* nodes  = (const float*)d_in[1];
    const float* g_node = (const float*)d_in[2];
    const float* g_edge = (const float*)d_in[3];
    const float* W      = (const float*)d_in[4];
    const float* bias   = (const float*)d_in[5];
    float* out = (float*)d_out;

    float*  rp  = (float*)d_ws;                 // 1024*64 f32 = 256 KB
    float*  cp  = rp + 1024 * DE;               // 256 KB
    __bf16* weg = (__bf16*)(cp + 1024 * DE);    // 8*64*8 bf16 = 8 KB

    prep_kernel<<<dim3(1025), dim3(64), 0, stream>>>(nodes, g_node, g_edge, W,
                                                     bias, rp, cp, weg);
    main_kernel<<<dim3(8192), dim3(256), 0, stream>>>(edges, rp, cp, weg, out);
}

// Round 9
// 56.566 us; speedup vs baseline: 1.8692x; 1.0751x over previous
//
#include <hip/hip_runtime.h>
#include <hip/hip_bf16.h>

#define DN 128
#define DE 64
#define NN 512

typedef __bf16 bf16x8 __attribute__((ext_vector_type(8)));
typedef float  f32x4  __attribute__((ext_vector_type(4)));

// -------- fused prep (unchanged) --------------------------------------------
__global__ void prep_kernel(const float* __restrict__ nodes,
                            const float* __restrict__ g_node,
                            const float* __restrict__ g_edge,
                            const float* __restrict__ W,
                            const float* __restrict__ bias,
                            float* __restrict__ rp, float* __restrict__ cp,
                            __bf16* __restrict__ weg) {
    const int l = threadIdx.x;  // 0..63
    if (blockIdx.x == 1024) {
        const int kg = l >> 4;
        for (int kh = 0; kh < 2; ++kh)
            for (int ct = 0; ct < 4; ++ct) {
                const int f = kh * 4 + ct;
                #pragma unroll
                for (int e = 0; e < 8; ++e) {
                    const int k   = kh * 32 + (e >> 2) * 16 + kg * 4 + (e & 3);
                    const int col = ct * 16 + (l & 15);
                    weg[(f * 64 + l) * 8 + e] =
                        (__bf16)(g_edge[k] * W[(2 * DN + k) * DE + col]);
                }
            }
        return;
    }
    const int row = blockIdx.x;      // b*N + i
    __shared__ float nn[DN];

    float x0 = nodes[row * DN + l];
    float x1 = nodes[row * DN + l + 64];
    float ssq = x0 * x0 + x1 * x1;
    #pragma unroll
    for (int m = 1; m < 64; m <<= 1) ssq += __shfl_xor(ssq, m, 64);
    float scale = rsqrtf(ssq * (1.0f / DN) + 1.1920929e-7f);
    nn[l]      = x0 * scale * g_node[l];
    nn[l + 64] = x1 * scale * g_node[l + 64];
    __syncthreads();

    float accr = bias[l];
    float accc = 0.0f;
    #pragma unroll 4
    for (int d = 0; d < DN; ++d) {
        float nd = nn[d];
        accr += nd * W[d * DE + l];          // Wr = W[0:128]
        accc += nd * W[(DN + d) * DE + l];   // Wc = W[128:256]
    }
    rp[row * DE + l] = accr;
    cp[row * DE + l] = accc;
}

// -------- main: R8 structure + NONTEMPORAL monotonic stores -----------------
// grid 8192 x 256, zero __syncthreads, wave-independent. Global loads/stores
// are plain ascending dwordx4 (lane l <-> byte l*16); XOR swizzle lives on
// the LDS side only. Single change vs R8: the final stores are nontemporal
// (out is write-once streaming data) so the 134 MB write stream stops
// evicting the edge buffer from L3. Stores are 8 full 128 B lines per
// instruction, so NT cannot fragment write-combining (unlike R3's scatter).
__global__ __launch_bounds__(256, 4) void main_kernel(
    const float* __restrict__ edges, const float* __restrict__ rp,
    const float* __restrict__ cp, const __bf16* __restrict__ weg,
    float* __restrict__ out) {
    __shared__ float lds[4096];            // 16 KB; wave w: [w*1024, +1024)
    const int bid = blockIdx.x;            // 0..8191
    const int row = bid >> 3;              // b*N + i
    const int t   = threadIdx.x;           // 0..255
    const int w   = t >> 6;
    const int l   = t & 63;
    const int r16 = l & 15;
    const int kg  = l >> 4;
    const int jt0 = (bid & 7) * 64;        // tile j base (64 rows)
    const int bN  = (row >> 9) << 9;       // b*512

    float* wlds = &lds[w * 1024];
    const float* tbase = edges + ((size_t)row * NN + jt0 + w * 16) * DE;
    float*       obase = out   + ((size_t)row * NN + jt0 + w * 16) * DE;

    // ---- P1: plain ascending loads (copy-identical), 4 KB per wave ----
    f32x4 st[4];
    #pragma unroll
    for (int i = 0; i < 4; ++i)
        st[i] = *reinterpret_cast<const f32x4*>(tbase + (i * 64 + l) * 4);

    // ---- reg operands (L1/L2-hot) ----
    bf16x8 wf[8];
    #pragma unroll
    for (int f = 0; f < 8; ++f)
        wf[f] = *reinterpret_cast<const bf16x8*>(weg + (f * 64 + l) * 8);

    const int j = jt0 + w * 16 + r16;       // this lane's global j
    const float* cprow = cp + (size_t)(bN + j) * DE + kg * 4;
    f32x4 cpv[4];
    #pragma unroll
    for (int c = 0; c < 4; ++c)
        cpv[c] = *reinterpret_cast<const f32x4*>(cprow + c * 16);

    f32x4 rpv[4];
    #pragma unroll
    for (int c = 0; c < 4; ++c)
        rpv[c] = *reinterpret_cast<const f32x4*>(rp + row * DE + c * 16 + kg * 4);

    // ---- P2: staged regs -> LDS, swizzled dest (chunk c of row r -> c^r) ----
    #pragma unroll
    for (int i = 0; i < 4; ++i) {
        const int C = i * 64 + l;           // wave-local chunk (linear global)
        const int r = C >> 4;               // row within wave's 16
        const int q = (C & 15) ^ r;         // swizzled LDS chunk slot
        *reinterpret_cast<f32x4*>(&wlds[r * 64 + q * 4]) = st[i];
    }

    // ---- P3: fragments from LDS (swizzled reads; wave-local ordering) ----
    f32x4 x[4];
    #pragma unroll
    for (int m = 0; m < 4; ++m) {
        const int q = (m * 4 + kg) ^ r16;
        x[m] = *reinterpret_cast<const f32x4*>(&wlds[r16 * 64 + q * 4]);
    }

    float ssq = 0.0f;
    #pragma unroll
    for (int m = 0; m < 4; ++m)
        #pragma unroll
        for (int e = 0; e < 4; ++e) ssq += x[m][e] * x[m][e];
    ssq += __shfl_xor(ssq, 16, 64);
    ssq += __shfl_xor(ssq, 32, 64);
    const float scale = rsqrtf(ssq * (1.0f / DE) + 1.1920929e-7f);

    bf16x8 a0, a1;
    #pragma unroll
    for (int e = 0; e < 4; ++e) {
        a0[e]     = (__bf16)x[0][e];   // k = kg*4+e
        a0[e + 4] = (__bf16)x[1][e];   // k = 16+kg*4+e
        a1[e]     = (__bf16)x[2][e];   // k = 32+kg*4+e
        a1[e + 4] = (__bf16)x[3][e];   // k = 48+kg*4+e
    }

    #pragma unroll
    for (int c = 0; c < 4; ++c) {
        f32x4 z = {0.f, 0.f, 0.f, 0.f};
        z = __builtin_amdgcn_mfma_f32_16x16x32_bf16(wf[c],     a0, z, 0, 0, 0);
        z = __builtin_amdgcn_mfma_f32_16x16x32_bf16(wf[4 + c], a1, z, 0, 0, 0);
        f32x4 o;
        #pragma unroll
        for (int r = 0; r < 4; ++r)
            o[r] = z[r] * scale + rpv[c][r] + cpv[c][r];
        const int qo = (c * 4 + kg) ^ r16;  // swizzled LDS write-back
        *reinterpret_cast<f32x4*>(&wlds[r16 * 64 + qo * 4]) = o;
    }

    // ---- P5: swizzled LDS read -> NONTEMPORAL ascending full-line stores ---
    #pragma unroll
    for (int i = 0; i < 4; ++i) {
        const int C = i * 64 + l;
        const int r = C >> 4;
        const int q = (C & 15) ^ r;
        f32x4 v = *reinterpret_cast<const f32x4*>(&wlds[r * 64 + q * 4]);
        __builtin_nontemporal_store(v,
            reinterpret_cast<f32x4*>(obase + (i * 64 + l) * 4));
    }
}

extern "C" void kernel_launch(void* const* d_in, const int* in_sizes, int n_in,
                              void* d_out, int out_size, void* d_ws, size_t ws_size,
                              hipStream_t stream) {
    const float* edges  = (const float*)d_in[0];
    const float* nodes  = (const float*)d_in[1];
    const float* g_node = (const float*)d_in[2];
    const float* g_edge = (const float*)d_in[3];
    const float* W      = (const float*)d_in[4];
    const float* bias   = (const float*)d_in[5];
    float* out = (float*)d_out;

    float*  rp  = (float*)d_ws;                 // 1024*64 f32 = 256 KB
    float*  cp  = rp + 1024 * DE;               // 256 KB
    __bf16* weg = (__bf16*)(cp + 1024 * DE);    // 8*64*8 bf16 = 8 KB

    prep_kernel<<<dim3(1025), dim3(64), 0, stream>>>(nodes, g_node, g_edge, W,
                                                     bias, rp, cp, weg);
    main_kernel<<<dim3(8192), dim3(256), 0, stream>>>(edges, rp, cp, weg, out);
}